// Round 12
// baseline (210.506 us; speedup 1.0000x reference)
//
#include <hip/hip_runtime.h>

typedef unsigned short ushort_t;
typedef unsigned int uint_t;

#define BKT_SHIFT 8            // 256 dst-nodes per bucket
#define BKT_NODES 256
#define NBKT_MAX 400           // >= ceil(100000/256)=391
#define EPB 8192               // edges per block in hist/scatter (512 thr x 16)
#define SCOL_CAP 8192          // LDS col staging in fine_fill (32 KB); mean bucket = 6400
#define NPB 64                 // nodes per block in agg_mlp
#define SCOL_N 2048            // LDS col cache per agg block (mean 1600, +11 sigma)

__device__ __forceinline__ ushort_t f2bf(float f) {
    unsigned u = __float_as_uint(f);
    unsigned r = (u + 0x7FFFu + ((u >> 16) & 1u)) >> 16;   // RNE
    return (ushort_t)r;
}
__device__ __forceinline__ float bflo(uint_t u) { return __uint_as_float(u << 16); }
__device__ __forceinline__ float bfhi(uint_t u) { return __uint_as_float(u & 0xFFFF0000u); }

// ---- ranked bucket sort (no global atomics) -----------------------------

// histA also performs the x -> bf16 conversion (fused to save a launch).
__global__ void histA(const float4* __restrict__ xin, ushort_t* __restrict__ xb, int n4,
                      const int* __restrict__ dst, int* __restrict__ hist,
                      int E, int NBKT) {
    __shared__ int lcnt[NBKT_MAX];
    int t = threadIdx.x, blk = blockIdx.x;
    // fused convert: grid-stride over N*8 float4s
    int gid = blk * 512 + t;
    int gstr = gridDim.x * 512;
    for (int i = gid; i < n4; i += gstr) {
        float4 v = xin[i];
        xb[i * 4 + 0] = f2bf(v.x);
        xb[i * 4 + 1] = f2bf(v.y);
        xb[i * 4 + 2] = f2bf(v.z);
        xb[i * 4 + 3] = f2bf(v.w);
    }
    for (int b = t; b < NBKT; b += 512) lcnt[b] = 0;
    __syncthreads();
    int e0 = blk * EPB;
    #pragma unroll
    for (int i = 0; i < 16; ++i) {
        int e = e0 + i * 512 + t;
        if (e < E) atomicAdd(&lcnt[dst[e] >> BKT_SHIFT], 1);
    }
    __syncthreads();
    for (int b = t; b < NBKT; b += 512) hist[blk * NBKT + b] = lcnt[b];
}

__global__ void colscan(int* __restrict__ hist, int* __restrict__ T,
                        int NBLK, int NBKT) {
    __shared__ int lds[256];
    int b = blockIdx.x, t = threadIdx.x;
    int j0 = t * 4;
    int v0 = (j0 + 0 < NBLK) ? hist[(j0 + 0) * NBKT + b] : 0;
    int v1 = (j0 + 1 < NBLK) ? hist[(j0 + 1) * NBKT + b] : 0;
    int v2 = (j0 + 2 < NBLK) ? hist[(j0 + 2) * NBKT + b] : 0;
    int v3 = (j0 + 3 < NBLK) ? hist[(j0 + 3) * NBKT + b] : 0;
    lds[t] = v0 + v1 + v2 + v3;
    __syncthreads();
    for (int off = 1; off < 256; off <<= 1) {
        int add = (t >= off) ? lds[t - off] : 0;
        __syncthreads();
        lds[t] += add;
        __syncthreads();
    }
    int p = (t == 0) ? 0 : lds[t - 1];
    if (j0 + 0 < NBLK) hist[(j0 + 0) * NBKT + b] = p;  p += v0;
    if (j0 + 1 < NBLK) hist[(j0 + 1) * NBKT + b] = p;  p += v1;
    if (j0 + 2 < NBLK) hist[(j0 + 2) * NBKT + b] = p;  p += v2;
    if (j0 + 3 < NBLK) hist[(j0 + 3) * NBKT + b] = p;
    if (t == 255) T[b] = lds[255];
}

__global__ void scan_small(const int* __restrict__ in, int* __restrict__ out,
                           int M, int E) {
    __shared__ int lds[1024];
    int t = threadIdx.x;
    int base = t * 4;
    int v0 = (base + 0 < M) ? in[base + 0] : 0;
    int v1 = (base + 1 < M) ? in[base + 1] : 0;
    int v2 = (base + 2 < M) ? in[base + 2] : 0;
    int v3 = (base + 3 < M) ? in[base + 3] : 0;
    lds[t] = v0 + v1 + v2 + v3;
    __syncthreads();
    for (int off = 1; off < 1024; off <<= 1) {
        int add = (t >= off) ? lds[t - off] : 0;
        __syncthreads();
        lds[t] += add;
        __syncthreads();
    }
    int p = (t == 0) ? 0 : lds[t - 1];
    if (base + 0 < M) out[base + 0] = p;  p += v0;
    if (base + 1 < M) out[base + 1] = p;  p += v1;
    if (base + 2 < M) out[base + 2] = p;  p += v2;
    if (base + 3 < M) out[base + 3] = p;
    if (t == 0) out[M] = E;
}

__global__ void scatter_kernel(const int* __restrict__ src, const int* __restrict__ dst,
                               const int* __restrict__ hist, const int* __restrict__ Tscan,
                               int* __restrict__ staged, int E, int NBKT) {
    __shared__ int lbase[NBKT_MAX];
    __shared__ int lcur[NBKT_MAX];
    int t = threadIdx.x, blk = blockIdx.x;
    for (int b = t; b < NBKT; b += 512) {
        lbase[b] = hist[blk * NBKT + b] + Tscan[b];
        lcur[b] = 0;
    }
    __syncthreads();
    int e0 = blk * EPB;
    #pragma unroll
    for (int i = 0; i < 16; ++i) {
        int e = e0 + i * 512 + t;
        if (e < E) {
            int d = dst[e], s = src[e];
            int b = d >> BKT_SHIFT;
            int r = atomicAdd(&lcur[b], 1);
            staged[lbase[b] + r] = ((d & (BKT_NODES - 1)) << 24) | s;
        }
    }
}

// One block per bucket: per-(node, src-quartile) LDS count -> 1024-wide scan
// (writes rp!) -> LDS place -> coalesced col flush. Quartile sub-sort keeps
// the agg gather sweep phase-local in src space.
__global__ void fine_fill(const int* __restrict__ staged, const int* __restrict__ Tscan,
                          int* __restrict__ rp, int* __restrict__ col,
                          int N, int E, int NBKT, int q1, int q2, int q3) {
    __shared__ int scnt[1024];   // [node][quartile]
    __shared__ int srel[1024];
    __shared__ int scur[1024];
    __shared__ int swsum[256];
    __shared__ int scol[SCOL_CAP];
    int b = blockIdx.x, t = threadIdx.x;
    int n0 = b << BKT_SHIFT;
    int nn = min(BKT_NODES, N - n0);
    int e0 = Tscan[b];
    int e1 = Tscan[b + 1];
    int m = e1 - e0;

    #pragma unroll
    for (int j = 0; j < 4; ++j) { scnt[t * 4 + j] = 0; scur[t * 4 + j] = 0; }
    __syncthreads();
    for (int i = t; i < m; i += 256) {
        int v = staged[e0 + i];
        int dl = ((unsigned)v) >> 24;
        int s = v & 0xFFFFFF;
        int q = (s >= q2) ? ((s >= q3) ? 3 : 2) : ((s >= q1) ? 1 : 0);
        atomicAdd(&scnt[dl * 4 + q], 1);
    }
    __syncthreads();
    int c0 = scnt[t * 4 + 0], c1 = scnt[t * 4 + 1];
    int c2 = scnt[t * 4 + 2], c3 = scnt[t * 4 + 3];
    int tot = c0 + c1 + c2 + c3;
    swsum[t] = tot;
    __syncthreads();
    for (int off = 1; off < 256; off <<= 1) {   // Hillis-Steele inclusive over nodes
        int add = (t >= off) ? swsum[t - off] : 0;
        __syncthreads();
        swsum[t] += add;
        __syncthreads();
    }
    int excl = swsum[t] - tot;                  // node-exclusive prefix
    srel[t * 4 + 0] = excl;
    srel[t * 4 + 1] = excl + c0;
    srel[t * 4 + 2] = excl + c0 + c1;
    srel[t * 4 + 3] = excl + c0 + c1 + c2;
    if (t < nn) rp[n0 + t] = e0 + excl;
    if (b == NBKT - 1 && t == 0) rp[N] = E;
    __syncthreads();

    if (m <= SCOL_CAP) {
        for (int i = t; i < m; i += 256) {
            int v = staged[e0 + i];
            int dl = ((unsigned)v) >> 24;
            int s = v & 0xFFFFFF;
            int q = (s >= q2) ? ((s >= q3) ? 3 : 2) : ((s >= q1) ? 1 : 0);
            int p = srel[dl * 4 + q] + atomicAdd(&scur[dl * 4 + q], 1);
            scol[p] = s;
        }
        __syncthreads();
        for (int i = t; i < m; i += 256) col[e0 + i] = scol[i];
    } else {  // statistically unreachable overflow fallback
        for (int i = t; i < m; i += 256) {
            int v = staged[e0 + i];
            int dl = ((unsigned)v) >> 24;
            int s = v & 0xFFFFFF;
            int q = (s >= q2) ? ((s >= q3) ? 3 : 2) : ((s >= q1) ? 1 : 0);
            int p = srel[dl * 4 + q] + atomicAdd(&scur[dl * 4 + q], 1);
            col[e0 + p] = s;
        }
    }
}

// ---- Fused aggregate + MLP ---------------------------------------------
// Block = 256 threads = 64 nodes x 4 lanes; each lane handles 8 channels via
// uint4 (16B = full 64B line across 4 lanes) => one gather instruction serves
// 16 edges. col prefetched to LDS nontemporal; sv/st1 padded for bank-freedom.

template <bool RELU_OUT, bool OUT_BF16>
__global__ void agg_mlp(const ushort_t* __restrict__ xin, const int* __restrict__ rp,
                        const int* __restrict__ col,
                        const float* __restrict__ Wa, const float* __restrict__ ba,
                        const float* __restrict__ Wb, const float* __restrict__ bb,
                        void* __restrict__ outv, int N) {
    __shared__ float sWa[32 * 16];
    __shared__ float sWb[16 * 32];
    __shared__ float sba[16], sbb[32];
    __shared__ float sv[NPB * 33];
    __shared__ float st1[NPB * 17];
    __shared__ int scol[SCOL_N];

    int t = threadIdx.x;
    sWa[t] = Wa[t];  sWa[t + 256] = Wa[t + 256];
    sWb[t] = Wb[t];  sWb[t + 256] = Wb[t + 256];
    if (t < 16) sba[t] = ba[t];
    if (t < 32) sbb[t] = bb[t];

    int base = blockIdx.x * NPB;
    int kb = rp[base];
    int kt = rp[min(base + NPB, N)];
    int tot = kt - kb;
    bool ovf = (tot > SCOL_N);
    if (!ovf) {
        for (int i = t; i < tot; i += 256)
            scol[i] = __builtin_nontemporal_load(col + kb + i);
    }
    __syncthreads();

    int ln = t >> 2;          // node slot 0..63
    int sl = t & 3;           // channels 8*sl .. 8*sl+7 (one uint4)
    int n  = base + ln;
    bool act = (n < N);
    const uint4* x4 = (const uint4*)xin;   // row = 4 uint4 (32 bf16)

    if (act) {
        uint4 us = x4[(size_t)n * 4 + sl];
        float v0 = bflo(us.x), v1 = bfhi(us.x), v2 = bflo(us.y), v3 = bfhi(us.y);
        float v4 = bflo(us.z), v5 = bfhi(us.z), v6 = bflo(us.w), v7 = bfhi(us.w);
        int ks = rp[n], ke = rp[n + 1];
        if (!ovf) {
            int k = ks - kb, kend = ke - kb;
            for (; k + 8 <= kend; k += 8) {
                int s0 = scol[k + 0], s1 = scol[k + 1], s2 = scol[k + 2], s3 = scol[k + 3];
                int s4 = scol[k + 4], s5 = scol[k + 5], s6 = scol[k + 6], s7 = scol[k + 7];
                uint4 u0 = x4[(size_t)s0 * 4 + sl];
                uint4 u1 = x4[(size_t)s1 * 4 + sl];
                uint4 u2 = x4[(size_t)s2 * 4 + sl];
                uint4 u3 = x4[(size_t)s3 * 4 + sl];
                uint4 u4 = x4[(size_t)s4 * 4 + sl];
                uint4 u5 = x4[(size_t)s5 * 4 + sl];
                uint4 u6 = x4[(size_t)s6 * 4 + sl];
                uint4 u7 = x4[(size_t)s7 * 4 + sl];
                v0 += ((bflo(u0.x) + bflo(u1.x)) + (bflo(u2.x) + bflo(u3.x)))
                    + ((bflo(u4.x) + bflo(u5.x)) + (bflo(u6.x) + bflo(u7.x)));
                v1 += ((bfhi(u0.x) + bfhi(u1.x)) + (bfhi(u2.x) + bfhi(u3.x)))
                    + ((bfhi(u4.x) + bfhi(u5.x)) + (bfhi(u6.x) + bfhi(u7.x)));
                v2 += ((bflo(u0.y) + bflo(u1.y)) + (bflo(u2.y) + bflo(u3.y)))
                    + ((bflo(u4.y) + bflo(u5.y)) + (bflo(u6.y) + bflo(u7.y)));
                v3 += ((bfhi(u0.y) + bfhi(u1.y)) + (bfhi(u2.y) + bfhi(u3.y)))
                    + ((bfhi(u4.y) + bfhi(u5.y)) + (bfhi(u6.y) + bfhi(u7.y)));
                v4 += ((bflo(u0.z) + bflo(u1.z)) + (bflo(u2.z) + bflo(u3.z)))
                    + ((bflo(u4.z) + bflo(u5.z)) + (bflo(u6.z) + bflo(u7.z)));
                v5 += ((bfhi(u0.z) + bfhi(u1.z)) + (bfhi(u2.z) + bfhi(u3.z)))
                    + ((bfhi(u4.z) + bfhi(u5.z)) + (bfhi(u6.z) + bfhi(u7.z)));
                v6 += ((bflo(u0.w) + bflo(u1.w)) + (bflo(u2.w) + bflo(u3.w)))
                    + ((bflo(u4.w) + bflo(u5.w)) + (bflo(u6.w) + bflo(u7.w)));
                v7 += ((bfhi(u0.w) + bfhi(u1.w)) + (bfhi(u2.w) + bfhi(u3.w)))
                    + ((bfhi(u4.w) + bfhi(u5.w)) + (bfhi(u6.w) + bfhi(u7.w)));
            }
            for (; k < kend; ++k) {
                uint4 u = x4[(size_t)scol[k] * 4 + sl];
                v0 += bflo(u.x); v1 += bfhi(u.x); v2 += bflo(u.y); v3 += bfhi(u.y);
                v4 += bflo(u.z); v5 += bfhi(u.z); v6 += bflo(u.w); v7 += bfhi(u.w);
            }
        } else {  // statistically unreachable
            for (int k = ks; k < ke; ++k) {
                uint4 u = x4[(size_t)col[k] * 4 + sl];
                v0 += bflo(u.x); v1 += bfhi(u.x); v2 += bflo(u.y); v3 += bfhi(u.y);
                v4 += bflo(u.z); v5 += bfhi(u.z); v6 += bflo(u.w); v7 += bfhi(u.w);
            }
        }
        int c0 = sl * 8;
        float* svp = &sv[ln * 33 + c0];
        svp[0] = v0; svp[1] = v1; svp[2] = v2; svp[3] = v3;
        svp[4] = v4; svp[5] = v5; svp[6] = v6; svp[7] = v7;
    }
    __syncthreads();

    if (act) {   // hidden units sl, sl+4, sl+8, sl+12 for node ln
        float h0 = sba[sl], h1 = sba[sl + 4], h2 = sba[sl + 8], h3 = sba[sl + 12];
        #pragma unroll
        for (int cc = 0; cc < 32; ++cc) {
            float vc = sv[ln * 33 + cc];
            h0 += vc * sWa[cc * 16 + sl];
            h1 += vc * sWa[cc * 16 + sl + 4];
            h2 += vc * sWa[cc * 16 + sl + 8];
            h3 += vc * sWa[cc * 16 + sl + 12];
        }
        st1[ln * 17 + sl]      = fmaxf(h0, 0.f);
        st1[ln * 17 + sl + 4]  = fmaxf(h1, 0.f);
        st1[ln * 17 + sl + 8]  = fmaxf(h2, 0.f);
        st1[ln * 17 + sl + 12] = fmaxf(h3, 0.f);
    }
    __syncthreads();

    if (act) {   // out channels 8*sl .. 8*sl+7 for node ln
        int c0 = sl * 8;
        float a0 = sbb[c0 + 0], a1 = sbb[c0 + 1], a2 = sbb[c0 + 2], a3 = sbb[c0 + 3];
        float a4 = sbb[c0 + 4], a5 = sbb[c0 + 5], a6 = sbb[c0 + 6], a7 = sbb[c0 + 7];
        #pragma unroll
        for (int j = 0; j < 16; ++j) {
            float hj = st1[ln * 17 + j];
            const float* w = &sWb[j * 32 + c0];
            a0 += hj * w[0]; a1 += hj * w[1]; a2 += hj * w[2]; a3 += hj * w[3];
            a4 += hj * w[4]; a5 += hj * w[5]; a6 += hj * w[6]; a7 += hj * w[7];
        }
        if (RELU_OUT) {
            a0 = fmaxf(a0, 0.f); a1 = fmaxf(a1, 0.f); a2 = fmaxf(a2, 0.f); a3 = fmaxf(a3, 0.f);
            a4 = fmaxf(a4, 0.f); a5 = fmaxf(a5, 0.f); a6 = fmaxf(a6, 0.f); a7 = fmaxf(a7, 0.f);
        }
        if (OUT_BF16) {
            uint_t* o = (uint_t*)outv + (size_t)n * 16 + sl * 4;
            __builtin_nontemporal_store((uint_t)f2bf(a0) | ((uint_t)f2bf(a1) << 16), o + 0);
            __builtin_nontemporal_store((uint_t)f2bf(a2) | ((uint_t)f2bf(a3) << 16), o + 1);
            __builtin_nontemporal_store((uint_t)f2bf(a4) | ((uint_t)f2bf(a5) << 16), o + 2);
            __builtin_nontemporal_store((uint_t)f2bf(a6) | ((uint_t)f2bf(a7) << 16), o + 3);
        } else {
            float* o = (float*)outv + (size_t)n * 32 + c0;
            __builtin_nontemporal_store(a0, o + 0);
            __builtin_nontemporal_store(a1, o + 1);
            __builtin_nontemporal_store(a2, o + 2);
            __builtin_nontemporal_store(a3, o + 3);
            __builtin_nontemporal_store(a4, o + 4);
            __builtin_nontemporal_store(a5, o + 5);
            __builtin_nontemporal_store(a6, o + 6);
            __builtin_nontemporal_store(a7, o + 7);
        }
    }
}

// ---- Launch -------------------------------------------------------------

extern "C" void kernel_launch(void* const* d_in, const int* in_sizes, int n_in,
                              void* d_out, int out_size, void* d_ws, size_t ws_size,
                              hipStream_t stream) {
    const float* x  = (const float*)d_in[0];
    const int*   ei = (const int*)d_in[1];
    const float* W1 = (const float*)d_in[2];
    const float* b1 = (const float*)d_in[3];
    const float* W2 = (const float*)d_in[4];
    const float* b2 = (const float*)d_in[5];
    const float* W3 = (const float*)d_in[6];
    const float* b3 = (const float*)d_in[7];
    const float* W4 = (const float*)d_in[8];
    const float* b4 = (const float*)d_in[9];

    const int N = in_sizes[0] / 32;
    const int E = in_sizes[1] / 2;
    const int* src = ei;
    const int* dst = ei + E;

    const int NBKT = (N + BKT_NODES - 1) >> BKT_SHIFT;   // 391
    const int NBLK = (E + EPB - 1) / EPB;                // 306

    char* ws = (char*)d_ws;
    size_t o = 0;
    auto alloc = [&](size_t bytes) -> char* {
        o = (o + 255) & ~(size_t)255;
        char* r = ws + o;
        o += bytes;
        return r;
    };
    int*      hist   = (int*)     alloc(4 * (size_t)NBLK * NBKT);
    int*      T      = (int*)     alloc(4 * (size_t)NBKT);
    int*      Tscan  = (int*)     alloc(4 * (size_t)(NBKT + 1));
    int*      staged = (int*)     alloc(4 * (size_t)E);
    int*      rp     = (int*)     alloc(4 * (size_t)(N + 1));
    int*      col    = (int*)     alloc(4 * (size_t)E);
    ushort_t* xb     = (ushort_t*)alloc(2 * (size_t)N * 32);
    ushort_t* hb     = (ushort_t*)alloc(2 * (size_t)N * 32);

    int n4 = N * 8;
    histA<<<NBLK, 512, 0, stream>>>((const float4*)x, xb, n4, dst, hist, E, NBKT);
    colscan<<<NBKT, 256, 0, stream>>>(hist, T, NBLK, NBKT);
    scan_small<<<1, 1024, 0, stream>>>(T, Tscan, NBKT, E);
    scatter_kernel<<<NBLK, 512, 0, stream>>>(src, dst, hist, Tscan, staged, E, NBKT);
    int q1 = N / 4, q2 = N / 2, q3 = (3 * N) / 4;
    fine_fill<<<NBKT, 256, 0, stream>>>(staged, Tscan, rp, col, N, E, NBKT, q1, q2, q3);

    agg_mlp<true,  true ><<<(N + NPB - 1) / NPB, 256, 0, stream>>>(xb, rp, col,
                                                                   W1, b1, W2, b2, hb, N);
    agg_mlp<false, false><<<(N + NPB - 1) / NPB, 256, 0, stream>>>(hb, rp, col,
                                                                   W3, b3, W4, b4, d_out, N);
}